// Round 10
// baseline (940.515 us; speedup 1.0000x reference)
//
#include <hip/hip_runtime.h>
#include <math.h>

#define NPIX 2304      // 48*48 patch positions
#define NDIM 243       // 3*9*9 patch dim
#define PDIM 256       // filters
#define BATCH 2
#define HO 48
#define IMGH 56
#define NCH 3
#define UNFOLD 12
#define FREQ 6

typedef __attribute__((ext_vector_type(8))) short bf16x8;
typedef __attribute__((ext_vector_type(4))) float f32x4;
typedef unsigned short ushort_t;

static const size_t NP256 = (size_t)NPIX * 256;
static const size_t sPN = (size_t)PDIM * NPIX;
static const size_t sNN = (size_t)NPIX * NPIX;

__device__ inline unsigned short f2bf(float x) {
    union { float f; unsigned u; } v; v.f = x;
    unsigned r = (v.u + 0x7FFFu + ((v.u >> 16) & 1u)) >> 16;
    return (unsigned short)r;
}
__device__ inline float bf2f(unsigned short u) {
    return __uint_as_float(((unsigned)u) << 16);
}

// async 16B/lane global->LDS; lds dest = uniform base + lane*16 (linear)
__device__ __forceinline__ void gload16(const ushort_t* g, ushort_t* s) {
    __builtin_amdgcn_global_load_lds(
        (__attribute__((address_space(1))) void*)g,
        (__attribute__((address_space(3))) void*)s, 16, 0, 0);
}

// ---------- intra-dispatch dependency sync ----------
// signal: block-drain (syncthreads implies vmcnt drain) + ONE release-add.
// wait: RELAXED spin (no cache ops per poll) + ONE acquire fence at exit.
__device__ __forceinline__ void sig1(unsigned* c) {
    __syncthreads();
    if (threadIdx.x == 0)
        __hip_atomic_fetch_add(c, 1u, __ATOMIC_RELEASE, __HIP_MEMORY_SCOPE_AGENT);
}
__device__ __forceinline__ void sig2(unsigned* c1, unsigned* c2) {
    __syncthreads();
    if (threadIdx.x == 0) {
        __hip_atomic_fetch_add(c1, 1u, __ATOMIC_RELEASE, __HIP_MEMORY_SCOPE_AGENT);
        __hip_atomic_fetch_add(c2, 1u, __ATOMIC_RELEASE, __HIP_MEMORY_SCOPE_AGENT);
    }
}
__device__ __forceinline__ void waitc1(unsigned* c, unsigned t) {
    if (threadIdx.x == 0) {
        unsigned g = 0;
        while (__hip_atomic_load(c, __ATOMIC_RELAXED, __HIP_MEMORY_SCOPE_AGENT) < t) {
            __builtin_amdgcn_s_sleep(2);
            if (++g > (1u << 27)) break;
        }
        __builtin_amdgcn_fence(__ATOMIC_ACQUIRE, "agent");
    }
    __syncthreads();
}
__device__ __forceinline__ void waitc2(unsigned* c1, unsigned t1, unsigned* c2, unsigned t2) {
    if (threadIdx.x == 0) {
        unsigned g = 0;
        while ((__hip_atomic_load(c1, __ATOMIC_RELAXED, __HIP_MEMORY_SCOPE_AGENT) < t1 ||
                __hip_atomic_load(c2, __ATOMIC_RELAXED, __HIP_MEMORY_SCOPE_AGENT) < t2)) {
            __builtin_amdgcn_s_sleep(2);
            if (++g > (1u << 27)) break;
        }
        __builtin_amdgcn_fence(__ATOMIC_ACQUIRE, "agent");
    }
    __syncthreads();
}

// upper-triangle tile decode: e in [0, 666) -> (mi<=ni), 36x36 tiles of 64
__device__ __forceinline__ void ut_decode(int e, int& mi, int& ni) {
    float f = (73.0f - sqrtf(5329.0f - 8.0f * (float)e)) * 0.5f;
    mi = (int)f;
    if (mi > 35) mi = 35;
    while (mi > 0 && e < mi * 36 - mi * (mi - 1) / 2) mi--;
    while (e >= (mi + 1) * 36 - (mi + 1) * mi / 2) mi++;
    ni = mi + (e - (mi * 36 - mi * (mi - 1) / 2));
}

#define EPI_G 0        // C fp32 (+ optional mirrored transpose); diag -> sqd
#define EPI_SPLITOUT 1 // Oh/Ol = split(acc)
#define EPI_ITER 2     // o=E1+E2-acc; C=o; C2=bf16(o*o)
#define EPI_WAI 3      // C=acc; C2=bf16(acc*acc)
#define EPI_ADDCOL 4   // C=acc+E1[b,n]
#define EPI_PROX 5     // shrink + POut fp32 + transposed split gT

// ---------------- shared NT split-bf16 MFMA GEMM tile body ----------------
template<int TM, int TN, int SPLIT, int BKU, int EPI>
__device__ __forceinline__ void gemm_tile(
    ushort_t* __restrict__ lds, int m0, int n0, int b, int mirror,
    const ushort_t* __restrict__ Ah, const ushort_t* __restrict__ Al,
    const ushort_t* __restrict__ Bh, const ushort_t* __restrict__ Bl,
    int ldA, int ldB, size_t sA, size_t sB, int K,
    float* __restrict__ C, ushort_t* __restrict__ C2,
    ushort_t* __restrict__ Oh, ushort_t* __restrict__ Ol,
    const float* __restrict__ E1, const float* __restrict__ E2,
    int ldC, size_t sC,
    const float* __restrict__ EA, const float* __restrict__ theta,
    float* __restrict__ sqd,
    float* __restrict__ POut, ushort_t* __restrict__ gTh, ushort_t* __restrict__ gTl) {

    constexpr int CA = TM / 16, CB = TN / 16;
    constexpr int CHUNKS = (1 + SPLIT) * (CA + CB);
    constexpr int UNITS = CHUNKS * BKU;
    constexpr int CPW = UNITS / 4;
    constexpr int BUFE = UNITS * 512;
    constexpr int WM = TM / 2, WN = TN / 2;
    constexpr int MF = WM / 16, NF = WN / 16;

    int tid = threadIdx.x;
    int w = tid >> 6, l = tid & 63, lm = l & 15, kh = l >> 4;
    int wm = (w >> 1) * WM, wn = (w & 1) * WN;

    const ushort_t* pAh = Ah + b * sA;
    const ushort_t* pAl = SPLIT ? Al + b * sA : nullptr;
    const ushort_t* pBh = Bh + b * sB;
    const ushort_t* pBl = SPLIT ? Bl + b * sB : nullptr;

    int srow = l >> 2;
    int sslot = ((l & 3) ^ ((l >> 3) & 3)) << 3;

    auto stage = [&](int bsel, int k0) {
        ushort_t* bb = lds + bsel * BUFE;
        #pragma unroll
        for (int i = 0; i < CPW; ++i) {
            int uu = w * CPW + i;
            int c = uu / BKU, u = uu % BKU;
            const ushort_t* src; int ld; int rowg;
            if (SPLIT) {
                if (c < CA)               { src = pAh; ld = ldA; rowg = m0 + c * 16; }
                else if (c < 2 * CA)      { src = pAl; ld = ldA; rowg = m0 + (c - CA) * 16; }
                else if (c < 2 * CA + CB) { src = pBh; ld = ldB; rowg = n0 + (c - 2 * CA) * 16; }
                else                      { src = pBl; ld = ldB; rowg = n0 + (c - 2 * CA - CB) * 16; }
            } else {
                if (c < CA) { src = pAh; ld = ldA; rowg = m0 + c * 16; }
                else        { src = pBh; ld = ldB; rowg = n0 + (c - CA) * 16; }
            }
            const ushort_t* g = src + (size_t)(rowg + srow) * ld + k0 + u * 32 + sslot;
            gload16(g, bb + (size_t)(c * BKU + u) * 512);
        }
    };

    f32x4 acc[MF][NF];
    #pragma unroll
    for (int mf = 0; mf < MF; ++mf)
        #pragma unroll
        for (int nf = 0; nf < NF; ++nf) acc[mf][nf] = (f32x4){0.f, 0.f, 0.f, 0.f};

    int sw = ((kh ^ ((lm >> 1) & 3)) << 3);
    const int NT = K / (32 * BKU);

    stage(0, 0);
    __syncthreads();
    for (int t = 0; t < NT; ++t) {
        if (t + 1 < NT) stage((t + 1) & 1, (t + 1) * (32 * BKU));
        ushort_t* bb = lds + (t & 1) * BUFE;
        ushort_t* LA_h = bb;
        ushort_t* LA_l = bb + CA * BKU * 512;
        ushort_t* LB_h = bb + (1 + SPLIT) * CA * BKU * 512;
        ushort_t* LB_l = LB_h + CB * BKU * 512;
        #pragma unroll
        for (int s = 0; s < BKU; ++s) {
            bf16x8 afh[MF], afl[MF], bfh[NF], bfl[NF];
            #pragma unroll
            for (int mf = 0; mf < MF; ++mf) {
                int off = ((wm >> 4) + mf) * (BKU * 512) + s * 512 + lm * 32 + sw;
                afh[mf] = *reinterpret_cast<const bf16x8*>(LA_h + off);
                if (SPLIT) afl[mf] = *reinterpret_cast<const bf16x8*>(LA_l + off);
            }
            #pragma unroll
            for (int nf = 0; nf < NF; ++nf) {
                int off = ((wn >> 4) + nf) * (BKU * 512) + s * 512 + lm * 32 + sw;
                bfh[nf] = *reinterpret_cast<const bf16x8*>(LB_h + off);
                if (SPLIT) bfl[nf] = *reinterpret_cast<const bf16x8*>(LB_l + off);
            }
            #pragma unroll
            for (int mf = 0; mf < MF; ++mf)
                #pragma unroll
                for (int nf = 0; nf < NF; ++nf) {
                    acc[mf][nf] = __builtin_amdgcn_mfma_f32_16x16x32_bf16(afh[mf], bfh[nf], acc[mf][nf], 0, 0, 0);
                    if (SPLIT) {
                        acc[mf][nf] = __builtin_amdgcn_mfma_f32_16x16x32_bf16(afh[mf], bfl[nf], acc[mf][nf], 0, 0, 0);
                        acc[mf][nf] = __builtin_amdgcn_mfma_f32_16x16x32_bf16(afl[mf], bfh[nf], acc[mf][nf], 0, 0, 0);
                    }
                }
        }
        __syncthreads();
    }

    if (EPI == EPI_PROX) {
        ushort_t* tbh = lds;
        ushort_t* tbl = lds + TN * (TM + 2);
        #pragma unroll
        for (int mf = 0; mf < MF; ++mf)
            #pragma unroll
            for (int nf = 0; nf < NF; ++nf)
                #pragma unroll
                for (int r = 0; r < 4; ++r) {
                    int pl = wm + mf * 16 + kh * 4 + r;
                    int jl = wn + nf * 16 + lm;
                    int gp = m0 + pl;
                    float n2 = sqrtf(acc[mf][nf][r] + 1e-8f);
                    size_t off = b * sC + (size_t)gp * ldC + (n0 + jl);
                    float v = fmaxf(1.f - theta[gp] / n2, 0.f) * EA[off];
                    POut[off] = v;
                    unsigned short h = f2bf(v);
                    tbh[jl * (TM + 2) + pl] = h;
                    tbl[jl * (TM + 2) + pl] = f2bf(v - bf2f(h));
                }
        __syncthreads();
        {
            constexpr int SEGS = TM / 8;
            constexpr int ITER = (TM * TN / 8 + 255) / 256;
            #pragma unroll
            for (int it = 0; it < ITER; ++it) {
                int idx = tid + it * 256;
                int jj = idx / SEGS, seg = (idx % SEGS) * 8;
                size_t go = ((size_t)b * NPIX + n0 + jj) * PDIM + m0 + seg;
                bf16x8 vh, vl;
                #pragma unroll
                for (int e = 0; e < 8; ++e) {
                    vh[e] = (short)tbh[jj * (TM + 2) + seg + e];
                    vl[e] = (short)tbl[jj * (TM + 2) + seg + e];
                }
                *reinterpret_cast<bf16x8*>(gTh + go) = vh;
                *reinterpret_cast<bf16x8*>(gTl + go) = vl;
            }
        }
        __syncthreads();
    } else {
        #pragma unroll
        for (int mf = 0; mf < MF; ++mf)
            #pragma unroll
            for (int nf = 0; nf < NF; ++nf)
                #pragma unroll
                for (int r = 0; r < 4; ++r) {
                    int gm = m0 + wm + mf * 16 + kh * 4 + r;
                    int gn = n0 + wn + nf * 16 + lm;
                    float v = acc[mf][nf][r];
                    size_t off = b * sC + (size_t)gm * ldC + gn;
                    if (EPI == EPI_G) {
                        C[off] = v;
                        if (gm == gn) sqd[b * NPIX + gm] = v;
                    } else if (EPI == EPI_SPLITOUT) {
                        unsigned short h = f2bf(v);
                        Oh[off] = h; Ol[off] = f2bf(v - bf2f(h));
                    } else if (EPI == EPI_ITER) {
                        float o = E1[off] + E2[off] - v;
                        C[off] = o;
                        C2[off] = f2bf(o * o);
                    } else if (EPI == EPI_WAI) {
                        C[off] = v;
                        C2[off] = f2bf(v * v);
                    } else { // EPI_ADDCOL
                        C[off] = v + E1[b * NPIX + gn];
                    }
                }
        if (EPI == EPI_G && mirror) {
            __syncthreads();
            float* ldsF = (float*)lds;
            #pragma unroll
            for (int mf = 0; mf < MF; ++mf)
                #pragma unroll
                for (int nf = 0; nf < NF; ++nf)
                    #pragma unroll
                    for (int r = 0; r < 4; ++r) {
                        int il = wm + mf * 16 + kh * 4 + r;
                        int jl = wn + nf * 16 + lm;
                        ldsF[jl * 66 + il] = acc[mf][nf][r];
                    }
            __syncthreads();
            int row = tid >> 2;
            int colq = (tid & 3) * 16;
            float* Crow = C + b * sC + (size_t)(n0 + row) * ldC + m0 + colq;
            #pragma unroll
            for (int e = 0; e < 16; e += 4) {
                float4 o = make_float4(ldsF[row * 66 + colq + e],
                                       ldsF[row * 66 + colq + e + 1],
                                       ldsF[row * 66 + colq + e + 2],
                                       ldsF[row * 66 + colq + e + 3]);
                *reinterpret_cast<float4*>(Crow + e) = o;
            }
            __syncthreads();
        }
    }
}

// ---------------- in-kernel row softmax (8 rows per 256-thread block) ----------------
template<int BLEND>
__device__ void softmax_rows(int s, const float* __restrict__ G,
                             const float* __restrict__ sqd,
                             ushort_t* __restrict__ Sbf,
                             const float* __restrict__ nu,
                             ushort_t* __restrict__ lds) {
    float* red = (float*)lds;
    int t = threadIdx.x;
    for (int rr = 0; rr < 8; ++rr) {
        __syncthreads();
        int row = s * 8 + rr;
        int b = row / NPIX, j = row % NPIX;
        const float* Grow = G + ((size_t)b * NPIX + j) * NPIX;
        const float* sqb = sqd + (size_t)b * NPIX;
        float v[9];
        float m = -1e30f;
        #pragma unroll
        for (int i = 0; i < 9; ++i) {
            int ix = t + i * 256;
            v[i] = 2.f * Grow[ix] - sqb[ix];
            m = fmaxf(m, v[i]);
        }
        red[t] = m; __syncthreads();
        for (int st = 128; st > 0; st >>= 1) { if (t < st) red[t] = fmaxf(red[t], red[t + st]); __syncthreads(); }
        m = red[0];
        __syncthreads();
        float ss = 0.f;
        #pragma unroll
        for (int i = 0; i < 9; ++i) { v[i] = expf(v[i] - m); ss += v[i]; }
        red[t] = ss; __syncthreads();
        for (int st = 128; st > 0; st >>= 1) { if (t < st) red[t] += red[t + st]; __syncthreads(); }
        float inv = 1.f / red[0];
        ushort_t* Srow = Sbf + ((size_t)b * NPIX + j) * NPIX;
        if (BLEND) {
            float nus = 1.f / (1.f + expf(-nu[0]));
            #pragma unroll
            for (int i = 0; i < 9; ++i) {
                int ix = t + i * 256;
                Srow[ix] = f2bf((1.f - nus) * bf2f(Srow[ix]) + nus * (v[i] * inv));
            }
        } else {
            #pragma unroll
            for (int i = 0; i < 9; ++i) Srow[t + i * 256] = f2bf(v[i] * inv);
        }
    }
}

// ---------------- shared pointer bundle ----------------
struct P {
    const ushort_t *XTsh, *XTsl, *XTuh, *XTul;
    const ushort_t *Wah, *Wal, *Mh, *Ml, *Qh, *Ql, *Wwh, *Wwl;
    ushort_t *Sbf, *A2, *gTh, *gTl, *HTh, *HTl;
    float *G, *sqd, *WaI, *Abuf, *gamma, *TR, *out;
    const float *nu, *lmb, *meanp;
    unsigned *cnt;
};

// ---------------- fused: symmetric gram (1332) || WaI (288, TM=64) ----------------
__global__ __launch_bounds__(256) void k_gram_wai(P p) {
    __shared__ ushort_t lds[16384];
    int id = blockIdx.x;
    if (id < 1332) {
        int bb = id / 666, e = id % 666, mi, ni;
        ut_decode(e, mi, ni);
        gemm_tile<64, 64, 1, 1, EPI_G>(lds, mi * 64, ni * 64, bb, (mi != ni),
            p.XTsh, p.XTsl, p.XTsh, p.XTsl, 256, 256, NP256, NP256, 256,
            p.G, nullptr, nullptr, nullptr, nullptr, nullptr, NPIX, sNN,
            nullptr, nullptr, p.sqd, nullptr, nullptr, nullptr);
    } else {
        int id2 = id - 1332;                    // [0,288)
        int L = ((id2 & 7) * 36) + (id2 >> 3);  // XCD-chunked
        int m = L % 4, n = (L / 4) % 36, b = L / 144;
        gemm_tile<64, 64, 1, 1, EPI_WAI>(lds, m * 64, n * 64, b, 0,
            p.Wah, p.Wal, p.XTuh, p.XTul, 256, 256, 0, NP256, 256,
            p.WaI, p.A2, nullptr, nullptr, nullptr, nullptr, NPIX, sPN,
            nullptr, nullptr, nullptr, nullptr, nullptr, nullptr);
    }
}

// ---------------- fused: softmax (576) -> prox (288), row-group counters ----------------
template<int BLEND>
__global__ __launch_bounds__(256) void k_sm_prox(P p, const float* EA, const float* theta, int cbase) {
    __shared__ ushort_t lds[16384];
    int id = blockIdx.x;
    if (id < 576) {
        softmax_rows<BLEND>(id, p.G, p.sqd, p.Sbf, p.nu, lds);
        sig1(p.cnt + cbase + (id >> 3));
    } else {
        int id2 = id - 576;                     // [0,288)
        int L = ((id2 & 7) * 36) + (id2 >> 3);
        int m = L % 4, n = (L / 4) % 36, b = L / 144;
        waitc1(p.cnt + cbase + b * 36 + n, 8);
        gemm_tile<64, 64, 0, 2, EPI_PROX>(lds, m * 64, n * 64, b, 0,
            p.A2, nullptr, p.Sbf, nullptr, NPIX, NPIX, sPN, sNN, NPIX,
            nullptr, nullptr, nullptr, nullptr, nullptr, nullptr, NPIX, sPN,
            EA, theta, nullptr, p.gamma, p.gTh, p.gTl);
    }
}

// ---------------- fused: iter_k (288) -> prox_{k+1} (288), m-RAW + n-WAR counters ----------------
__global__ __launch_bounds__(256) void k_iterprox(P p, int kk, const float* theta) {
    __shared__ ushort_t lds[16384];
    unsigned* itm = p.cnt + 144 + kk * 16;
    unsigned* itn = p.cnt + 400 + kk * 72;
    int id = blockIdx.x;
    if (id < 288) {
        int L = ((id & 7) * 36) + (id >> 3);
        int m = L % 4, n = (L / 4) % 36, b = L / 144;
        gemm_tile<64, 64, 1, 1, EPI_ITER>(lds, m * 64, n * 64, b, 0,
            p.Mh, p.Ml, p.gTh, p.gTl, 256, 256, 0, NP256, 256,
            p.Abuf, p.A2, nullptr, nullptr, p.WaI, p.gamma, NPIX, sPN,
            nullptr, nullptr, nullptr, nullptr, nullptr, nullptr);
        sig2(itm + b * 4 + m, itn + b * 36 + n);
    } else {
        int id2 = id - 288;
        int L = ((id2 & 7) * 36) + (id2 >> 3);
        int m = L % 4, n = (L / 4) % 36, b = L / 144;
        waitc2(itm + b * 4 + m, 36, itn + b * 36 + n, 4);
        gemm_tile<64, 64, 0, 2, EPI_PROX>(lds, m * 64, n * 64, b, 0,
            p.A2, nullptr, p.Sbf, nullptr, NPIX, NPIX, sPN, sNN, NPIX,
            nullptr, nullptr, nullptr, nullptr, nullptr, nullptr, NPIX, sPN,
            p.Abuf, theta, nullptr, p.gamma, p.gTh, p.gTl);
    }
}

// ---------------- fused: HT = gT@Q (288) || iter_6 (288), independent ----------------
__global__ __launch_bounds__(256) void k_ht_iter(P p) {
    __shared__ ushort_t lds[16384];
    int id = blockIdx.x;
    if (id < 288) {
        int L = ((id & 7) * 36) + (id >> 3);
        int m = L % 36, n = (L / 36) % 4, b = L / 144;
        gemm_tile<64, 64, 1, 1, EPI_SPLITOUT>(lds, m * 64, n * 64, b, 0,
            p.gTh, p.gTl, p.Qh, p.Ql, 256, 256, NP256, 0, 256,
            nullptr, nullptr, p.HTh, p.HTl, nullptr, nullptr, 256, NP256,
            nullptr, nullptr, nullptr, nullptr, nullptr, nullptr);
    } else {
        int id2 = id - 288;
        int L = ((id2 & 7) * 36) + (id2 >> 3);
        int m = L % 4, n = (L / 4) % 36, b = L / 144;
        gemm_tile<64, 64, 1, 1, EPI_ITER>(lds, m * 64, n * 64, b, 0,
            p.Mh, p.Ml, p.gTh, p.gTl, 256, 256, 0, NP256, 256,
            p.Abuf, p.A2, nullptr, nullptr, p.WaI, p.gamma, NPIX, sPN,
            nullptr, nullptr, nullptr, nullptr, nullptr, nullptr);
    }
}

// ---------------- symmetric gram refresh: G = gT @ HT^T (upper + mirror) ----------------
__global__ __launch_bounds__(256) void k_gramref(P p) {
    __shared__ ushort_t lds[16384];
    int id = blockIdx.x;
    int bb = id / 666, e = id % 666, mi, ni;
    ut_decode(e, mi, ni);
    gemm_tile<64, 64, 1, 1, EPI_G>(lds, mi * 64, ni * 64, bb, (mi != ni),
        p.gTh, p.gTl, p.HTh, p.HTl, 256, 256, NP256, NP256, 256,
        p.G, nullptr, nullptr, nullptr, nullptr, nullptr, NPIX, sNN,
        nullptr, nullptr, p.sqd, nullptr, nullptr, nullptr);
}

// ---------------- final: out_all = Ww @ gamma + mean ----------------
__global__ __launch_bounds__(256) void k_final(P p) {
    __shared__ ushort_t lds[16384];
    int id = blockIdx.x;
    int L = ((id & 7) * 36) + (id >> 3);
    int m = L % 4, n = (L / 4) % 36, b = L / 144;
    gemm_tile<64, 64, 1, 1, EPI_ADDCOL>(lds, m * 64, n * 64, b, 0,
        p.Wwh, p.Wwl, p.gTh, p.gTl, 256, 256, 0, NP256, 256,
        p.TR, nullptr, nullptr, nullptr, p.meanp, nullptr, NPIX, (size_t)256 * NPIX,
        nullptr, nullptr, nullptr, nullptr, nullptr, nullptr);
}

// ---------------- precompute: M=Wa@Wd, Q=Ww^T diag(std0^2) Ww, Wa/Ww split-bf16 (K-pad 256) ----
__global__ __launch_bounds__(1024) void k_precomp(const float* __restrict__ Wa,
                                                  const float* __restrict__ Wd,
                                                  const float* __restrict__ Ww,
                                                  const float* __restrict__ std0,
                                                  ushort_t* __restrict__ Mh, ushort_t* __restrict__ Ml,
                                                  ushort_t* __restrict__ Qh, ushort_t* __restrict__ Ql,
                                                  ushort_t* __restrict__ Wah, ushort_t* __restrict__ Wal,
                                                  ushort_t* __restrict__ Wwh, ushort_t* __restrict__ Wwl) {
    int p = blockIdx.x;
    int tid = threadIdx.x;
    int q = tid & 255, cc = tid >> 8;
    float m = 0.f, qv = 0.f;
    for (int c = cc; c < NDIM; c += 4) {
        m += Wa[p * NDIM + c] * Wd[c * PDIM + q];
        float s = std0[c];
        qv += s * s * Ww[c * PDIM + p] * Ww[c * PDIM + q];
    }
    __shared__ float sm[2][1024];
    sm[0][tid] = m; sm[1][tid] = qv;
    __syncthreads();
    if (cc == 0) {
        m  = sm[0][q] + sm[0][q + 256] + sm[0][q + 512] + sm[0][q + 768];
        qv = sm[1][q] + sm[1][q + 256] + sm[1][q + 512] + sm[1][q + 768];
        int off = p * PDIM + q;
        unsigned short h = f2bf(m);
        Mh[off] = h; Ml[off] = f2bf(m - bf2f(h));
        h = f2bf(qv);
        Qh[off] = h; Ql[off] = f2bf(qv - bf2f(h));
        float wa = (q < NDIM) ? Wa[p * NDIM + q] : 0.f;
        h = f2bf(wa);
        Wah[off] = h; Wal[off] = f2bf(wa - bf2f(h));
        float ww = (p < NDIM) ? Ww[p * PDIM + q] : 0.f;
        h = f2bf(ww);
        Wwh[off] = h; Wwl[off] = f2bf(ww - bf2f(h));
    }
}

// ---------------- im2col: mean-sub, emit scaled + unscaled transposed split-bf16 (K-pad 256) ----
__global__ __launch_bounds__(256) void k_im2col(const float* __restrict__ I,
                                                float* __restrict__ meanp,
                                                ushort_t* __restrict__ XTsh, ushort_t* __restrict__ XTsl,
                                                ushort_t* __restrict__ XTuh, ushort_t* __restrict__ XTul,
                                                const float* __restrict__ std0) {
    int col = blockIdx.x % NPIX;
    int b = blockIdx.x / NPIX;
    int oi = col / HO, oj = col % HO;
    int t = threadIdx.x;
    float v = 0.f;
    if (t < NDIM) {
        int c = t / 81, rem = t % 81, ki = rem / 9, kj = rem % 9;
        v = I[((size_t)(b * NCH + c) * IMGH + (oi + ki)) * IMGH + (oj + kj)];
    }
    __shared__ float red[256];
    red[t] = v;
    __syncthreads();
    for (int s = 128; s > 0; s >>= 1) {
        if (t < s) red[t] += red[t + s];
        __syncthreads();
    }
    float mean = red[0] / (float)NDIM;
    float xu = (t < NDIM) ? v - mean : 0.f;
    float xs = (t < NDIM) ? xu * std0[t] : 0.f;
    if (t == 0) meanp[b * NPIX + col] = mean;
    size_t xo = ((size_t)b * NPIX + col) * 256 + t;
    unsigned short h = f2bf(xu);
    XTuh[xo] = h; XTul[xo] = f2bf(xu - bf2f(h));
    h = f2bf(xs);
    XTsh[xo] = h; XTsl[xo] = f2bf(xs - bf2f(h));
}

// ---------------- col2im with overlap averaging ----------------
__global__ void k_col2im(const float* __restrict__ T, float* __restrict__ out) {
    int idx = blockIdx.x * blockDim.x + threadIdx.x;
    int total = BATCH * NCH * IMGH * IMGH;
    if (idx >= total) return;
    int x = idx % IMGH; int tmp = idx / IMGH;
    int y = tmp % IMGH; tmp /= IMGH;
    int c = tmp % NCH; int b = tmp / NCH;
    int kiLo = max(0, y - (HO - 1)), kiHi = min(8, y);
    int kjLo = max(0, x - (HO - 1)), kjHi = min(8, x);
    float s = 0.f;
    for (int ki = kiLo; ki <= kiHi; ++ki)
        for (int kj = kjLo; kj <= kjHi; ++kj) {
            int ch = c * 81 + ki * 9 + kj;
            s += T[((size_t)b * 256 + ch) * NPIX + (y - ki) * HO + (x - kj)];
        }
    int cnt = (kiHi - kiLo + 1) * (kjHi - kjLo + 1);
    out[idx] = s / (float)cnt;
}

extern "C" void kernel_launch(void* const* d_in, const int* in_sizes, int n_in,
                              void* d_out, int out_size, void* d_ws, size_t ws_size,
                              hipStream_t stream) {
    const float* I    = (const float*)d_in[0];
    const float* Wa   = (const float*)d_in[1];  // (256,243)
    const float* Wd   = (const float*)d_in[2];  // (243,256)
    const float* Ww   = (const float*)d_in[3];  // (243,256)
    const float* std0 = (const float*)d_in[4];  // (243)
    const float* lmb  = (const float*)d_in[5];  // (12,256)
    const float* nu   = (const float*)d_in[6];  // (1)
    float* out = (float*)d_out;
    float* ws = (float*)d_ws;

    size_t off = 0;
    auto alloc = [&](size_t n) { float* p = ws + off; off += (n + 63) & ~(size_t)63; return p; };
    auto allocU = [&](size_t n) { return (ushort_t*)alloc((n + 1) / 2); };

    unsigned* cnt = (unsigned*)alloc(2048);
    float* WaI   = alloc((size_t)BATCH * PDIM * NPIX);
    float* Abuf  = alloc((size_t)BATCH * PDIM * NPIX);
    float* gamma = alloc((size_t)BATCH * PDIM * NPIX);
    float* TR    = alloc((size_t)BATCH * 256 * NPIX);
    float* G     = alloc((size_t)BATCH * NPIX * NPIX);
    ushort_t* Sbf  = allocU((size_t)BATCH * NPIX * NPIX);
    ushort_t* A2   = allocU((size_t)BATCH * PDIM * NPIX);
    ushort_t* XTsh = allocU(BATCH * NP256);
    ushort_t* XTsl = allocU(BATCH * NP256);
    ushort_t* XTuh = allocU(BATCH * NP256);
    ushort_t* XTul = allocU(BATCH * NP256);
    ushort_t* gTh  = allocU(BATCH * NP256);
    ushort_t* gTl  = allocU(BATCH * NP256);
    ushort_t* HTh  = allocU(BATCH * NP256);
    ushort_t* HTl  = allocU(BATCH * NP256);
    ushort_t* Mh   = allocU(PDIM * PDIM);
    ushort_t* Ml   = allocU(PDIM * PDIM);
    ushort_t* Qh   = allocU(PDIM * PDIM);
    ushort_t* Ql   = allocU(PDIM * PDIM);
    ushort_t* Wah  = allocU(PDIM * PDIM);
    ushort_t* Wal  = allocU(PDIM * PDIM);
    ushort_t* Wwh  = allocU(PDIM * PDIM);
    ushort_t* Wwl  = allocU(PDIM * PDIM);
    float* meanp = alloc((size_t)BATCH * NPIX);
    float* sqd   = alloc((size_t)BATCH * NPIX);
    (void)ws_size; (void)in_sizes; (void)n_in; (void)out_size;

    dim3 blk(256);

    hipMemsetAsync((void*)cnt, 0, 2048 * sizeof(unsigned), stream);
    k_precomp<<<dim3(PDIM), dim3(1024), 0, stream>>>(Wa, Wd, Ww, std0, Mh, Ml, Qh, Ql, Wah, Wal, Wwh, Wwl);
    k_im2col<<<dim3(BATCH * NPIX), blk, 0, stream>>>(I, meanp, XTsh, XTsl, XTuh, XTul, std0);

    P p;
    p.XTsh = XTsh; p.XTsl = XTsl; p.XTuh = XTuh; p.XTul = XTul;
    p.Wah = Wah; p.Wal = Wal; p.Mh = Mh; p.Ml = Ml;
    p.Qh = Qh; p.Ql = Ql; p.Wwh = Wwh; p.Wwl = Wwl;
    p.Sbf = Sbf; p.A2 = A2; p.gTh = gTh; p.gTl = gTl; p.HTh = HTh; p.HTl = HTl;
    p.G = G; p.sqd = sqd; p.WaI = WaI; p.Abuf = Abuf; p.gamma = gamma;
    p.TR = TR; p.out = out;
    p.nu = nu; p.lmb = lmb; p.meanp = meanp;
    p.cnt = cnt;

    // gram (symmetric, upper+mirror, diag->sqd) || WaI (+A2)
    k_gram_wai<<<dim3(1620), blk, 0, stream>>>(p);
    // softmax0 -> prox0 (fused, row-group counters; counter base 0)
    k_sm_prox<0><<<dim3(864), blk, 0, stream>>>(p, WaI, lmb, 0);
    // iterations k = 0..5: {iter_k -> prox_{k+1}}
    for (int kk = 0; kk < 6; ++kk)
        k_iterprox<<<dim3(576), blk, 0, stream>>>(p, kk, lmb + (size_t)(kk + 1) * PDIM);
    // k=6 refresh: {HT || iter_6}; gram-refresh; {blend-softmax -> prox_7} (counter base 72)
    k_ht_iter<<<dim3(576), blk, 0, stream>>>(p);
    k_gramref<<<dim3(1332), blk, 0, stream>>>(p);
    k_sm_prox<1><<<dim3(864), blk, 0, stream>>>(p, Abuf, lmb + (size_t)7 * PDIM, 72);
    // iterations k = 7..10: {iter_k -> prox_{k+1}}
    for (int kk = 6; kk < 10; ++kk)
        k_iterprox<<<dim3(576), blk, 0, stream>>>(p, kk, lmb + (size_t)(kk + 2) * PDIM);
    // final projection + fold
    k_final<<<dim3(288), blk, 0, stream>>>(p);
    k_col2im<<<dim3((BATCH * NCH * IMGH * IMGH + 255) / 256), blk, 0, stream>>>(TR, out);
}

// Round 11
// 442.476 us; speedup vs baseline: 2.1256x; 2.1256x over previous
//
#include <hip/hip_runtime.h>
#include <math.h>

#define NPIX 2304      // 48*48 patch positions
#define NDIM 243       // 3*9*9 patch dim
#define PDIM 256       // filters
#define BATCH 2
#define HO 48
#define IMGH 56
#define NCH 3
#define UNFOLD 12
#define FREQ 6

typedef __attribute__((ext_vector_type(8))) short bf16x8;
typedef __attribute__((ext_vector_type(4))) float f32x4;
typedef unsigned short ushort_t;

static const size_t NP256 = (size_t)NPIX * 256;
static const size_t sPN = (size_t)PDIM * NPIX;
static const size_t sNN = (size_t)NPIX * NPIX;

__device__ inline unsigned short f2bf(float x) {
    union { float f; unsigned u; } v; v.f = x;
    unsigned r = (v.u + 0x7FFFu + ((v.u >> 16) & 1u)) >> 16;
    return (unsigned short)r;
}
__device__ inline float bf2f(unsigned short u) {
    return __uint_as_float(((unsigned)u) << 16);
}

// async 16B/lane global->LDS; lds dest = uniform base + lane*16 (linear)
__device__ __forceinline__ void gload16(const ushort_t* g, ushort_t* s) {
    __builtin_amdgcn_global_load_lds(
        (__attribute__((address_space(1))) void*)g,
        (__attribute__((address_space(3))) void*)s, 16, 0, 0);
}

// upper-triangle tile decode: e in [0, 666) -> (mi<=ni), 36x36 tiles of 64
__device__ __forceinline__ void ut_decode(int e, int& mi, int& ni) {
    float f = (73.0f - sqrtf(5329.0f - 8.0f * (float)e)) * 0.5f;
    mi = (int)f;
    if (mi > 35) mi = 35;
    while (mi > 0 && e < mi * 36 - mi * (mi - 1) / 2) mi--;
    while (e >= (mi + 1) * 36 - (mi + 1) * mi / 2) mi++;
    ni = mi + (e - (mi * 36 - mi * (mi - 1) / 2));
}

#define EPI_G 0        // C fp32 (+ optional mirrored transpose); diag -> sqd
#define EPI_SPLITOUT 1 // Oh/Ol = split(acc)
#define EPI_ITER 2     // o = E1 - acc; C=o; C2=bf16(o*o)   (M' = M - I folded)
#define EPI_WAI 3      // C=acc; C2=bf16(acc*acc)
#define EPI_ADDCOL 4   // C=acc+E1[b,n]
#define EPI_PROX 5     // shrink + transposed split gT (no fp32 gamma)

// ---------------- shared NT split-bf16 MFMA GEMM tile body ----------------
template<int TM, int TN, int SPLIT, int BKU, int EPI>
__device__ __forceinline__ void gemm_tile(
    ushort_t* __restrict__ lds, int m0, int n0, int b, int mirror,
    const ushort_t* __restrict__ Ah, const ushort_t* __restrict__ Al,
    const ushort_t* __restrict__ Bh, const ushort_t* __restrict__ Bl,
    int ldA, int ldB, size_t sA, size_t sB, int K,
    float* __restrict__ C, ushort_t* __restrict__ C2,
    ushort_t* __restrict__ Oh, ushort_t* __restrict__ Ol,
    const float* __restrict__ E1,
    int ldC, size_t sC,
    const float* __restrict__ EA, const float* __restrict__ theta,
    float* __restrict__ sqd,
    ushort_t* __restrict__ gTh, ushort_t* __restrict__ gTl) {

    constexpr int CA = TM / 16, CB = TN / 16;
    constexpr int CHUNKS = (1 + SPLIT) * (CA + CB);
    constexpr int UNITS = CHUNKS * BKU;
    constexpr int CPW = UNITS / 4;
    constexpr int BUFE = UNITS * 512;
    constexpr int WM = TM / 2, WN = TN / 2;
    constexpr int MF = WM / 16, NF = WN / 16;

    int tid = threadIdx.x;
    int w = tid >> 6, l = tid & 63, lm = l & 15, kh = l >> 4;
    int wm = (w >> 1) * WM, wn = (w & 1) * WN;

    const ushort_t* pAh = Ah + b * sA;
    const ushort_t* pAl = SPLIT ? Al + b * sA : nullptr;
    const ushort_t* pBh = Bh + b * sB;
    const ushort_t* pBl = SPLIT ? Bl + b * sB : nullptr;

    int srow = l >> 2;
    int sslot = ((l & 3) ^ ((l >> 3) & 3)) << 3;

    auto stage = [&](int bsel, int k0) {
        ushort_t* bb = lds + bsel * BUFE;
        #pragma unroll
        for (int i = 0; i < CPW; ++i) {
            int uu = w * CPW + i;
            int c = uu / BKU, u = uu % BKU;
            const ushort_t* src; int ld; int rowg;
            if (SPLIT) {
                if (c < CA)               { src = pAh; ld = ldA; rowg = m0 + c * 16; }
                else if (c < 2 * CA)      { src = pAl; ld = ldA; rowg = m0 + (c - CA) * 16; }
                else if (c < 2 * CA + CB) { src = pBh; ld = ldB; rowg = n0 + (c - 2 * CA) * 16; }
                else                      { src = pBl; ld = ldB; rowg = n0 + (c - 2 * CA - CB) * 16; }
            } else {
                if (c < CA) { src = pAh; ld = ldA; rowg = m0 + c * 16; }
                else        { src = pBh; ld = ldB; rowg = n0 + (c - CA) * 16; }
            }
            const ushort_t* g = src + (size_t)(rowg + srow) * ld + k0 + u * 32 + sslot;
            gload16(g, bb + (size_t)(c * BKU + u) * 512);
        }
    };

    f32x4 acc[MF][NF];
    #pragma unroll
    for (int mf = 0; mf < MF; ++mf)
        #pragma unroll
        for (int nf = 0; nf < NF; ++nf) acc[mf][nf] = (f32x4){0.f, 0.f, 0.f, 0.f};

    int sw = ((kh ^ ((lm >> 1) & 3)) << 3);
    const int NT = K / (32 * BKU);

    stage(0, 0);
    __syncthreads();
    for (int t = 0; t < NT; ++t) {
        if (t + 1 < NT) stage((t + 1) & 1, (t + 1) * (32 * BKU));
        ushort_t* bb = lds + (t & 1) * BUFE;
        ushort_t* LA_h = bb;
        ushort_t* LA_l = bb + CA * BKU * 512;
        ushort_t* LB_h = bb + (1 + SPLIT) * CA * BKU * 512;
        ushort_t* LB_l = LB_h + CB * BKU * 512;
        #pragma unroll
        for (int s = 0; s < BKU; ++s) {
            bf16x8 afh[MF], afl[MF], bfh[NF], bfl[NF];
            #pragma unroll
            for (int mf = 0; mf < MF; ++mf) {
                int off = ((wm >> 4) + mf) * (BKU * 512) + s * 512 + lm * 32 + sw;
                afh[mf] = *reinterpret_cast<const bf16x8*>(LA_h + off);
                if (SPLIT) afl[mf] = *reinterpret_cast<const bf16x8*>(LA_l + off);
            }
            #pragma unroll
            for (int nf = 0; nf < NF; ++nf) {
                int off = ((wn >> 4) + nf) * (BKU * 512) + s * 512 + lm * 32 + sw;
                bfh[nf] = *reinterpret_cast<const bf16x8*>(LB_h + off);
                if (SPLIT) bfl[nf] = *reinterpret_cast<const bf16x8*>(LB_l + off);
            }
            #pragma unroll
            for (int mf = 0; mf < MF; ++mf)
                #pragma unroll
                for (int nf = 0; nf < NF; ++nf) {
                    acc[mf][nf] = __builtin_amdgcn_mfma_f32_16x16x32_bf16(afh[mf], bfh[nf], acc[mf][nf], 0, 0, 0);
                    if (SPLIT) {
                        acc[mf][nf] = __builtin_amdgcn_mfma_f32_16x16x32_bf16(afh[mf], bfl[nf], acc[mf][nf], 0, 0, 0);
                        acc[mf][nf] = __builtin_amdgcn_mfma_f32_16x16x32_bf16(afl[mf], bfh[nf], acc[mf][nf], 0, 0, 0);
                    }
                }
        }
        __syncthreads();
    }

    if (EPI == EPI_PROX) {
        ushort_t* tbh = lds;
        ushort_t* tbl = lds + TN * (TM + 2);
        #pragma unroll
        for (int mf = 0; mf < MF; ++mf)
            #pragma unroll
            for (int nf = 0; nf < NF; ++nf)
                #pragma unroll
                for (int r = 0; r < 4; ++r) {
                    int pl = wm + mf * 16 + kh * 4 + r;
                    int jl = wn + nf * 16 + lm;
                    int gp = m0 + pl;
                    float n2 = sqrtf(acc[mf][nf][r] + 1e-8f);
                    size_t off = b * sC + (size_t)gp * ldC + (n0 + jl);
                    float v = fmaxf(1.f - theta[gp] / n2, 0.f) * EA[off];
                    unsigned short h = f2bf(v);
                    tbh[jl * (TM + 2) + pl] = h;
                    tbl[jl * (TM + 2) + pl] = f2bf(v - bf2f(h));
                }
        __syncthreads();
        {
            constexpr int SEGS = TM / 8;
            constexpr int ITER = (TM * TN / 8 + 255) / 256;
            #pragma unroll
            for (int it = 0; it < ITER; ++it) {
                int idx = tid + it * 256;
                int jj = idx / SEGS, seg = (idx % SEGS) * 8;
                size_t go = ((size_t)b * NPIX + n0 + jj) * PDIM + m0 + seg;
                bf16x8 vh, vl;
                #pragma unroll
                for (int e = 0; e < 8; ++e) {
                    vh[e] = (short)tbh[jj * (TM + 2) + seg + e];
                    vl[e] = (short)tbl[jj * (TM + 2) + seg + e];
                }
                *reinterpret_cast<bf16x8*>(gTh + go) = vh;
                *reinterpret_cast<bf16x8*>(gTl + go) = vl;
            }
        }
        __syncthreads();
    } else {
        #pragma unroll
        for (int mf = 0; mf < MF; ++mf)
            #pragma unroll
            for (int nf = 0; nf < NF; ++nf)
                #pragma unroll
                for (int r = 0; r < 4; ++r) {
                    int gm = m0 + wm + mf * 16 + kh * 4 + r;
                    int gn = n0 + wn + nf * 16 + lm;
                    float v = acc[mf][nf][r];
                    size_t off = b * sC + (size_t)gm * ldC + gn;
                    if (EPI == EPI_G) {
                        C[off] = v;
                        if (gm == gn) sqd[b * NPIX + gm] = v;
                    } else if (EPI == EPI_SPLITOUT) {
                        unsigned short h = f2bf(v);
                        Oh[off] = h; Ol[off] = f2bf(v - bf2f(h));
                    } else if (EPI == EPI_ITER) {
                        float o = E1[off] - v;      // A = WaI - (M-I)gamma
                        C[off] = o;
                        C2[off] = f2bf(o * o);
                    } else if (EPI == EPI_WAI) {
                        C[off] = v;
                        C2[off] = f2bf(v * v);
                    } else { // EPI_ADDCOL
                        C[off] = v + E1[b * NPIX + gn];
                    }
                }
        if (EPI == EPI_G && mirror) {
            __syncthreads();
            float* ldsF = (float*)lds;
            #pragma unroll
            for (int mf = 0; mf < MF; ++mf)
                #pragma unroll
                for (int nf = 0; nf < NF; ++nf)
                    #pragma unroll
                    for (int r = 0; r < 4; ++r) {
                        int il = wm + mf * 16 + kh * 4 + r;
                        int jl = wn + nf * 16 + lm;
                        ldsF[jl * 66 + il] = acc[mf][nf][r];
                    }
            __syncthreads();
            int row = tid >> 2;
            int colq = (tid & 3) * 16;
            float* Crow = C + b * sC + (size_t)(n0 + row) * ldC + m0 + colq;
            #pragma unroll
            for (int e = 0; e < 16; e += 4) {
                float4 o = make_float4(ldsF[row * 66 + colq + e],
                                       ldsF[row * 66 + colq + e + 1],
                                       ldsF[row * 66 + colq + e + 2],
                                       ldsF[row * 66 + colq + e + 3]);
                *reinterpret_cast<float4*>(Crow + e) = o;
            }
            __syncthreads();
        }
    }
}

// ---------------- shared pointer bundle ----------------
struct P {
    const ushort_t *XTsh, *XTsl, *XTuh, *XTul;
    const ushort_t *Wah, *Wal, *Mh, *Ml, *Qh, *Ql, *Wwh, *Wwl;
    ushort_t *Sbf, *A2, *gTh, *gTl, *HTh, *HTl;
    float *G, *sqd, *WaI, *Abuf, *TR, *out;
    const float *nu, *lmb, *meanp;
};

// 576-block decode (TM=64/TN=32 over PDIM x NPIX), XCD-chunked, m-fastest
__device__ __forceinline__ void dec576(int id, int& m, int& n, int& b) {
    int L = ((id & 7) * 72) + (id >> 3);
    m = L % 4; n = (L / 4) % 72; b = L / 288;
}

// ---------------- fused: symmetric gram (1332) || WaI (288, 64x64) ----------------
__global__ __launch_bounds__(256) void k_gram_wai(P p) {
    __shared__ ushort_t lds[16384];
    int id = blockIdx.x;
    if (id < 1332) {
        int bb = id / 666, e = id % 666, mi, ni;
        ut_decode(e, mi, ni);
        gemm_tile<64, 64, 1, 1, EPI_G>(lds, mi * 64, ni * 64, bb, (mi != ni),
            p.XTsh, p.XTsl, p.XTsh, p.XTsl, 256, 256, NP256, NP256, 256,
            p.G, nullptr, nullptr, nullptr, nullptr, NPIX, sNN,
            nullptr, nullptr, p.sqd, nullptr, nullptr);
    } else {
        int id2 = id - 1332;                    // [0,288)
        int L = ((id2 & 7) * 36) + (id2 >> 3);
        int m = L % 4, n = (L / 4) % 36, b = L / 144;
        gemm_tile<64, 64, 1, 1, EPI_WAI>(lds, m * 64, n * 64, b, 0,
            p.Wah, p.Wal, p.XTuh, p.XTul, 256, 256, 0, NP256, 256,
            p.WaI, p.A2, nullptr, nullptr, nullptr, NPIX, sPN,
            nullptr, nullptr, nullptr, nullptr, nullptr);
    }
}

// ---------------- prox: gamma = shrink(EA) -> gT split-bf16 ----------------
__global__ __launch_bounds__(256) void k_prox(P p, const float* EA, const float* theta) {
    __shared__ ushort_t lds[24576];   // 48 KB
    int m, n, b; dec576(blockIdx.x, m, n, b);
    gemm_tile<64, 32, 0, 4, EPI_PROX>(lds, m * 64, n * 32, b, 0,
        p.A2, nullptr, p.Sbf, nullptr, NPIX, NPIX, sPN, sNN, NPIX,
        nullptr, nullptr, nullptr, nullptr, nullptr, NPIX, sPN,
        EA, theta, nullptr, p.gTh, p.gTl);
}

// ---------------- iter: A = WaI - M' @ gamma ; A2 = bf16(A^2) ----------------
__global__ __launch_bounds__(256) void k_iter(P p) {
    __shared__ ushort_t lds[24576];
    int m, n, b; dec576(blockIdx.x, m, n, b);
    gemm_tile<64, 32, 1, 2, EPI_ITER>(lds, m * 64, n * 32, b, 0,
        p.Mh, p.Ml, p.gTh, p.gTl, 256, 256, 0, NP256, 256,
        p.Abuf, p.A2, nullptr, nullptr, p.WaI, NPIX, sPN,
        nullptr, nullptr, nullptr, nullptr, nullptr);
}

// ---------------- fused: HT = gT@Q (576) || iter_6 (576) ----------------
__global__ __launch_bounds__(256) void k_ht_iter(P p) {
    __shared__ ushort_t lds[24576];
    int id = blockIdx.x;
    if (id < 576) {
        int L = ((id & 7) * 72) + (id >> 3);
        int m = L % 36, n = (L / 36) % 8, b = L / 288;
        gemm_tile<64, 32, 1, 2, EPI_SPLITOUT>(lds, m * 64, n * 32, b, 0,
            p.gTh, p.gTl, p.Qh, p.Ql, 256, 256, NP256, 0, 256,
            nullptr, nullptr, p.HTh, p.HTl, nullptr, 256, NP256,
            nullptr, nullptr, nullptr, nullptr, nullptr);
    } else {
        int m, n, b; dec576(id - 576, m, n, b);
        gemm_tile<64, 32, 1, 2, EPI_ITER>(lds, m * 64, n * 32, b, 0,
            p.Mh, p.Ml, p.gTh, p.gTl, 256, 256, 0, NP256, 256,
            p.Abuf, p.A2, nullptr, nullptr, p.WaI, NPIX, sPN,
            nullptr, nullptr, nullptr, nullptr, nullptr);
    }
}

// ---------------- symmetric gram refresh: G = gT @ HT^T (upper + mirror) ----------------
__global__ __launch_bounds__(256) void k_gramref(P p) {
    __shared__ ushort_t lds[16384];
    int id = blockIdx.x;
    int bb = id / 666, e = id % 666, mi, ni;
    ut_decode(e, mi, ni);
    gemm_tile<64, 64, 1, 1, EPI_G>(lds, mi * 64, ni * 64, bb, (mi != ni),
        p.gTh, p.gTl, p.HTh, p.HTl, 256, 256, NP256, NP256, 256,
        p.G, nullptr, nullptr, nullptr, nullptr, NPIX, sNN,
        nullptr, nullptr, p.sqd, nullptr, nullptr);
}

// ---------------- final: out_all = Ww @ gamma + mean ----------------
__global__ __launch_bounds__(256) void k_final(P p) {
    __shared__ ushort_t lds[24576];
    int m, n, b; dec576(blockIdx.x, m, n, b);
    gemm_tile<64, 32, 1, 2, EPI_ADDCOL>(lds, m * 64, n * 32, b, 0,
        p.Wwh, p.Wwl, p.gTh, p.gTl, 256, 256, 0, NP256, 256,
        p.TR, nullptr, nullptr, nullptr, p.meanp, NPIX, (size_t)256 * NPIX,
        nullptr, nullptr, nullptr, nullptr, nullptr);
}

// ---------------- precompute: M'=Wa@Wd - I, Q=Ww^T diag(std0^2) Ww, split-bf16 weights ----
__global__ __launch_bounds__(1024) void k_precomp(const float* __restrict__ Wa,
                                                  const float* __restrict__ Wd,
                                                  const float* __restrict__ Ww,
                                                  const float* __restrict__ std0,
                                                  ushort_t* __restrict__ Mh, ushort_t* __restrict__ Ml,
                                                  ushort_t* __restrict__ Qh, ushort_t* __restrict__ Ql,
                                                  ushort_t* __restrict__ Wah, ushort_t* __restrict__ Wal,
                                                  ushort_t* __restrict__ Wwh, ushort_t* __restrict__ Wwl) {
    int p = blockIdx.x;
    int tid = threadIdx.x;
    int q = tid & 255, cc = tid >> 8;
    float m = 0.f, qv = 0.f;
    for (int c = cc; c < NDIM; c += 4) {
        m += Wa[p * NDIM + c] * Wd[c * PDIM + q];
        float s = std0[c];
        qv += s * s * Ww[c * PDIM + p] * Ww[c * PDIM + q];
    }
    __shared__ float sm[2][1024];
    sm[0][tid] = m; sm[1][tid] = qv;
    __syncthreads();
    if (cc == 0) {
        m  = sm[0][q] + sm[0][q + 256] + sm[0][q + 512] + sm[0][q + 768];
        qv = sm[1][q] + sm[1][q + 256] + sm[1][q + 512] + sm[1][q + 768];
        if (p == q) m -= 1.0f;      // M' = M - I
        int off = p * PDIM + q;
        unsigned short h = f2bf(m);
        Mh[off] = h; Ml[off] = f2bf(m - bf2f(h));
        h = f2bf(qv);
        Qh[off] = h; Ql[off] = f2bf(qv - bf2f(h));
        float wa = (q < NDIM) ? Wa[p * NDIM + q] : 0.f;
        h = f2bf(wa);
        Wah[off] = h; Wal[off] = f2bf(wa - bf2f(h));
        float ww = (p < NDIM) ? Ww[p * PDIM + q] : 0.f;
        h = f2bf(ww);
        Wwh[off] = h; Wwl[off] = f2bf(ww - bf2f(h));
    }
}

// ---------------- im2col: mean-sub, emit scaled + unscaled transposed split-bf16 ----
__global__ __launch_bounds__(256) void k_im2col(const float* __restrict__ I,
                                                float* __restrict__ meanp,
                                                ushort_t* __restrict__ XTsh, ushort_t* __restrict__ XTsl,
                                                ushort_t* __restrict__ XTuh, ushort_t* __restrict__ XTul,
                                                const float* __restrict__ std0) {
    int col = blockIdx.x % NPIX;
    int b = blockIdx.x / NPIX;
    int oi = col / HO, oj = col % HO;
    int t = threadIdx.x;
    float v = 0.f;
    if (t < NDIM) {
        int c = t / 81, rem = t % 81, ki = rem / 9, kj = rem % 9;
        v = I[((size_t)(b * NCH + c) * IMGH + (oi + ki)) * IMGH + (oj + kj)];
    }
    __shared__ float red[256];
    red[t] = v;
    __syncthreads();
    for (int s = 128; s > 0; s >>= 1) {
        if (t < s) red[t] += red[t + s];
        __syncthreads();
    }
    float mean = red[0] / (float)NDIM;
    float xu = (t < NDIM) ? v - mean : 0.f;
    float xs = (t < NDIM) ? xu * std0[t] : 0.f;
    if (t == 0) meanp[b * NPIX + col] = mean;
    size_t xo = ((size_t)b * NPIX + col) * 256 + t;
    unsigned short h = f2bf(xu);
    XTuh[xo] = h; XTul[xo] = f2bf(xu - bf2f(h));
    h = f2bf(xs);
    XTsh[xo] = h; XTsl[xo] = f2bf(xs - bf2f(h));
}

// ---------------- row softmax (register-resident) -> bf16 transposed sim ----------------
template<int BLEND>
__global__ __launch_bounds__(256) void k_softmax(const float* __restrict__ G,
                                                 const float* __restrict__ sq,
                                                 ushort_t* __restrict__ Sbf,
                                                 const float* __restrict__ nu) {
    int b = blockIdx.x / NPIX;
    int j = blockIdx.x % NPIX;
    const float* Grow = G + ((size_t)b * NPIX + j) * NPIX;
    const float* sqb = sq + (size_t)b * NPIX;
    int t = threadIdx.x;
    float v[9];
    float m = -1e30f;
    #pragma unroll
    for (int i = 0; i < 9; ++i) {
        int ix = t + i * 256;
        v[i] = 2.f * Grow[ix] - sqb[ix];
        m = fmaxf(m, v[i]);
    }
    __shared__ float red[256];
    red[t] = m; __syncthreads();
    for (int s = 128; s > 0; s >>= 1) { if (t < s) red[t] = fmaxf(red[t], red[t+s]); __syncthreads(); }
    m = red[0];
    __syncthreads();
    float ss = 0.f;
    #pragma unroll
    for (int i = 0; i < 9; ++i) { v[i] = expf(v[i] - m); ss += v[i]; }
    red[t] = ss; __syncthreads();
    for (int s = 128; s > 0; s >>= 1) { if (t < s) red[t] += red[t+s]; __syncthreads(); }
    float inv = 1.f / red[0];
    ushort_t* Srow = Sbf + ((size_t)b * NPIX + j) * NPIX;
    if (BLEND) {
        float nus = 1.f / (1.f + expf(-nu[0]));
        #pragma unroll
        for (int i = 0; i < 9; ++i) {
            int ix = t + i * 256;
            Srow[ix] = f2bf((1.f - nus) * bf2f(Srow[ix]) + nus * (v[i] * inv));
        }
    } else {
        #pragma unroll
        for (int i = 0; i < 9; ++i) Srow[t + i * 256] = f2bf(v[i] * inv);
    }
}

// ---------------- col2im with overlap averaging ----------------
__global__ void k_col2im(const float* __restrict__ T, float* __restrict__ out) {
    int idx = blockIdx.x * blockDim.x + threadIdx.x;
    int total = BATCH * NCH * IMGH * IMGH;
    if (idx >= total) return;
    int x = idx % IMGH; int tmp = idx / IMGH;
    int y = tmp % IMGH; tmp /= IMGH;
    int c = tmp % NCH; int b = tmp / NCH;
    int kiLo = max(0, y - (HO - 1)), kiHi = min(8, y);
    int kjLo = max(0, x - (HO - 1)), kjHi = min(8, x);
    float s = 0.f;
    for (int ki = kiLo; ki <= kiHi; ++ki)
        for (int kj = kjLo; kj <= kjHi; ++kj) {
            int ch = c * 81 + ki * 9 + kj;
            s += T[((size_t)b * 256 + ch) * NPIX + (y - ki) * HO + (x - kj)];
        }
    int cnt = (kiHi - kiLo + 1) * (kjHi - kjLo + 1);
    out[idx] = s / (float)cnt;
}

extern "C" void kernel_launch(void* const* d_in, const int* in_sizes, int n_in,
                              void* d_out, int out_size, void* d_ws, size_t ws_size,
                              hipStream_t stream) {
    const float* I    = (const float*)d_in[0];
    const float* Wa   = (const float*)d_in[1];  // (256,243)
    const float* Wd   = (const float*)d_in[2];  // (243,256)
    const float* Ww   = (const float*)d_in[3];  // (243,256)
    const float* std0 = (const float*)d_in[4];  // (243)
    const float* lmb  = (const float*)d_in[5];  // (12,256)
    const float* nu   = (const float*)d_in[6];  // (1)
    float* out = (float*)d_out;
    float* ws = (float*)d_ws;

    size_t off = 0;
    auto alloc = [&](size_t n) { float* p = ws + off; off += (n + 63) & ~(size_t)63; return p; };
    auto allocU = [&](size_t n) { return (ushort_t*)alloc((n + 1) / 2); };

    float* WaI   = alloc((size_t)BATCH * PDIM * NPIX);
    float* Abuf  = alloc((size_t)BATCH * PDIM * NPIX);
    float* TR    = alloc((size_t)BATCH * 256 * NPIX);
    float* G     = alloc((size_t)BATCH * NPIX * NPIX);
    ushort_t* Sbf  = allocU((size_t)BATCH * NPIX * NPIX);
    ushort_t* A2   = allocU((size_t)BATCH * PDIM * NPIX);
    ushort_t* XTsh = allocU(BATCH * NP256);
    ushort_t* XTsl = allocU(BATCH * NP256);
    ushort_t* XTuh = allocU(BATCH * NP256);
    ushort_t* XTul = allocU(BATCH * NP256);
    ushort_t* gTh  = allocU(BATCH * NP256);
    ushort_t* gTl  = allocU(BATCH * NP256);
    ushort_t* HTh  = allocU(BATCH * NP256);
    ushort_t* HTl  = allocU(BATCH * NP256);
    ushort_t* Mh   = allocU(PDIM * PDIM);
    ushort_t* Ml   = allocU(PDIM * PDIM);
    ushort_t* Qh   = allocU(PDIM * PDIM);
    ushort_t* Ql   = allocU(PDIM * PDIM);
    ushort_t* Wah  = allocU(PDIM * PDIM);
    ushort_t* Wal  = allocU(PDIM * PDIM);
    ushort_t* Wwh  = allocU(PDIM * PDIM);
    ushort_t* Wwl  = allocU(PDIM * PDIM);
    float* meanp = alloc((size_t)BATCH * NPIX);
    float* sqd   = alloc((size_t)BATCH * NPIX);
    (void)ws_size; (void)in_sizes; (void)n_in; (void)out_size;

    dim3 blk(256);

    k_precomp<<<dim3(PDIM), dim3(1024), 0, stream>>>(Wa, Wd, Ww, std0, Mh, Ml, Qh, Ql, Wah, Wal, Wwh, Wwl);
    k_im2col<<<dim3(BATCH * NPIX), blk, 0, stream>>>(I, meanp, XTsh, XTsl, XTuh, XTul, std0);

    P p;
    p.XTsh = XTsh; p.XTsl = XTsl; p.XTuh = XTuh; p.XTul = XTul;
    p.Wah = Wah; p.Wal = Wal; p.Mh = Mh; p.Ml = Ml;
    p.Qh = Qh; p.Ql = Ql; p.Wwh = Wwh; p.Wwl = Wwl;
    p.Sbf = Sbf; p.A2 = A2; p.gTh = gTh; p.gTl = gTl; p.HTh = HTh; p.HTl = HTl;
    p.G = G; p.sqd = sqd; p.WaI = WaI; p.Abuf = Abuf;
    p.TR = TR; p.out = out;
    p.nu = nu; p.lmb = lmb; p.meanp = meanp;

    // gram (symmetric, upper+mirror, diag->sqd) || WaI (+A2)
    k_gram_wai<<<dim3(1620), blk, 0, stream>>>(p);
    k_softmax<0><<<dim3(BATCH * NPIX), blk, 0, stream>>>(G, sqd, Sbf, nu);
    // gamma_0 = prox(WaI)
    k_prox<<<dim3(576), blk, 0, stream>>>(p, WaI, lmb);

    for (int k = 0; k < UNFOLD - 1; ++k) {
        if (k == FREQ) {
            // {HT = gT@Q || iter_6}; gram-refresh; blend-softmax
            k_ht_iter<<<dim3(1152), blk, 0, stream>>>(p);
            k_gramref<<<dim3(1332), blk, 0, stream>>>(p);
            k_softmax<1><<<dim3(BATCH * NPIX), blk, 0, stream>>>(G, sqd, Sbf, nu);
        } else {
            // A = WaI - M'@gamma ; A2 = bf16(A^2)
            k_iter<<<dim3(576), blk, 0, stream>>>(p);
        }
        // gamma_{k+1} = prox(A)
        k_prox<<<dim3(576), blk, 0, stream>>>(p, Abuf, lmb + (size_t)(k + 1) * PDIM);
    }
    // out_all = Ww @ gamma + mean; fold
    k_final<<<dim3(576), blk, 0, stream>>>(p);
    k_col2im<<<dim3((BATCH * NCH * IMGH * IMGH + 255) / 256), blk, 0, stream>>>(TR, out);
}